// Round 11
// baseline (574.176 us; speedup 1.0000x reference)
//
#include <hip/hip_runtime.h>
#include <stdint.h>

#define EPS_F 1e-7f

typedef float f32x4 __attribute__((ext_vector_type(4)));
typedef float f32x8 __attribute__((ext_vector_type(8)));
typedef short short8 __attribute__((ext_vector_type(8)));
typedef unsigned short u16;
typedef unsigned short ushort4v __attribute__((ext_vector_type(4)));
typedef unsigned short ushort8v __attribute__((ext_vector_type(8)));
typedef unsigned int uint4v __attribute__((ext_vector_type(4)));

__device__ __forceinline__ short f2bf(float f) {
  unsigned u = __float_as_uint(f);
  unsigned r = u + 0x7FFFu + ((u >> 16) & 1u);
  return (short)(r >> 16);
}
__device__ __forceinline__ float bf2f(u16 u) {
  return __uint_as_float((unsigned)u << 16);
}

// ---------------------------------------------------------------------------
// Encoder tables:  f(x) = relu(x*w1 + b1) @ W2 + b2  (scalar x -> R^256)
// 129 segments with knots at -b1_j/w1_j.  segsel: segment ids for x=-1, x=+1.
// Merged: block 0 = node encoder, block 1 = edge encoder (+segsel).
// ---------------------------------------------------------------------------
__global__ void build_meta2_kernel(const float* __restrict__ nw1, const float* __restrict__ nb1,
                                   const float* __restrict__ ew1, const float* __restrict__ eb1,
                                   float* __restrict__ knN, int* __restrict__ rankN,
                                   int* __restrict__ act0N,
                                   float* __restrict__ knE, int* __restrict__ rankE,
                                   int* __restrict__ act0E, int* __restrict__ segsel) {
  __shared__ float s_kx[128];
  __shared__ float s_sorted[128];
  int isE = blockIdx.x;
  const float* w1 = isE ? ew1 : nw1;
  const float* b1 = isE ? eb1 : nb1;
  float* knots = isE ? knE : knN;
  int* jrank = isE ? rankE : rankN;
  int* act0 = isE ? act0E : act0N;
  int t = threadIdx.x;  // 0..127
  float w = w1[t], b = b1[t];
  float kx = (w != 0.0f) ? (-b / w) : 3.4e38f;
  s_kx[t] = kx;
  int a0 = (w < 0.0f) || (w == 0.0f && b > 0.0f);  // active at x = -inf
  __syncthreads();
  int r = 0;
  for (int i = 0; i < 128; ++i) {
    float o = s_kx[i];
    if (o < kx || (o == kx && i < t)) ++r;
  }
  jrank[t] = r;
  act0[t] = a0;
  knots[r] = kx;
  s_sorted[r] = kx;
  __syncthreads();
  if (t == 0 && isE) {
    int lo = 0, hi = 128;
    while (lo < hi) { int m = (lo + hi) >> 1; if (s_sorted[m] < -1.0f) lo = m + 1; else hi = m; }
    segsel[0] = lo;
    lo = 0; hi = 128;
    while (lo < hi) { int m = (lo + hi) >> 1; if (s_sorted[m] < 1.0f) lo = m + 1; else hi = m; }
    segsel[1] = lo;
  }
}

// per-segment coefficients, both encoders: blocks 0..128 = node, 129..257 = edge
__global__ void build_seg2_kernel(const float* __restrict__ nw1, const float* __restrict__ nb1,
                                  const float* __restrict__ nw2, const float* __restrict__ nb2,
                                  const float* __restrict__ ew1, const float* __restrict__ eb1,
                                  const float* __restrict__ ew2, const float* __restrict__ eb2,
                                  const int* __restrict__ rankN, const int* __restrict__ act0N,
                                  const int* __restrict__ rankE, const int* __restrict__ act0E,
                                  float* __restrict__ AN, float* __restrict__ BN,
                                  unsigned* __restrict__ ABE) {
  int isE = (blockIdx.x >= 129);
  int s = isE ? (blockIdx.x - 129) : blockIdx.x;  // 0..128
  int t = threadIdx.x;                            // 0..255
  const float* w1 = isE ? ew1 : nw1;
  const float* b1 = isE ? eb1 : nb1;
  const float* w2 = isE ? ew2 : nw2;
  const float* b2 = isE ? eb2 : nb2;
  const int* jrank = isE ? rankE : rankN;
  const int* act0 = isE ? act0E : act0N;
  __shared__ float s_w1[128], s_b1[128];
  __shared__ int s_on[128];
  if (t < 128) {
    s_w1[t] = w1[t];
    s_b1[t] = b1[t];
    s_on[t] = act0[t] ^ (jrank[t] < s ? 1 : 0);
  }
  __syncthreads();
  float A = 0.0f, B = b2[t];
#pragma unroll 4
  for (int j = 0; j < 128; ++j) {
    if (s_on[j]) {
      float w2v = w2[j * 256 + t];
      A = fmaf(s_w1[j], w2v, A);
      B = fmaf(s_b1[j], w2v, B);
    }
  }
  if (!isE) {
    AN[s * 256 + t] = A;
    BN[s * 256 + t] = B;
  } else {
    unsigned a = (unsigned)(u16)f2bf(A);
    unsigned bb = (unsigned)(u16)f2bf(B);
    ABE[s * 256 + t] = a | (bb << 16);
  }
}

// fused: node encoder (blocks [0,gEnc)), counts zero ([gEnc,gEnc+gZero)),
// weight convert ([gEnc+gZero, +1024))
__global__ void enc_fused_kernel(const float* __restrict__ in, int nrows, int gEnc, int gZero,
                                 const float* __restrict__ knots, const float* __restrict__ segA,
                                 const float* __restrict__ segB, u16* __restrict__ outbf,
                                 int* __restrict__ counts,
                                 const float* __restrict__ W, short* __restrict__ WT) {
  int bid = blockIdx.x;
  int t = threadIdx.x;
  if (bid < gEnc) {
    __shared__ float s_kx[128];
    if (t < 128) s_kx[t] = knots[t];
    __syncthreads();
    int r0 = bid * 16;
    int rEnd = r0 + 16;
    if (rEnd > nrows) rEnd = nrows;
    for (int r = r0; r < rEnd; ++r) {
      float x = in[r];
      int lo = 0, hi = 128;
      while (lo < hi) { int mid = (lo + hi) >> 1; if (s_kx[mid] < x) lo = mid + 1; else hi = mid; }
      outbf[(size_t)r * 256 + t] = (u16)f2bf(fmaf(segA[lo * 256 + t], x, segB[lo * 256 + t]));
    }
  } else if (bid < gEnc + gZero) {
    int i = (bid - gEnc) * 256 + t;
    if (i < nrows) counts[i] = 0;
  } else {
    int cb = bid - gEnc - gZero;           // 0..1023
    int l = cb >> 8, nn = cb & 255, k = t; // gnn_w [4][256][256] -> WT [4][256][256]^T
    WT[((size_t)l * 256 + nn) * 256 + k] = f2bf(W[((size_t)l * 256 + k) * 256 + nn]);
  }
}

__global__ void hist_kernel(const int* __restrict__ dst, int E, int* __restrict__ counts) {
  int i = blockIdx.x * blockDim.x + threadIdx.x;
  if (i < E) atomicAdd(&counts[dst[i]], 1);
}

// 3-phase exclusive scan of counts[0..n) -> row_start[0..n], row_start[n]=E
__global__ void scan_p1_kernel(const int* __restrict__ counts, int n,
                               int* __restrict__ blocksums) {
  __shared__ int tmp[256];
  int t = threadIdx.x;
  int i = blockIdx.x * 256 + t;
  tmp[t] = (i < n) ? counts[i] : 0;
  __syncthreads();
  for (int off = 128; off > 0; off >>= 1) {
    if (t < off) tmp[t] += tmp[t + off];
    __syncthreads();
  }
  if (t == 0) blocksums[blockIdx.x] = tmp[0];
}

__global__ void scan_p2_kernel(int* __restrict__ blocksums, int nb,
                               int* __restrict__ row_start, int n) {
  __shared__ int tmp[256];
  int t = threadIdx.x;
  int v = (t < nb) ? blocksums[t] : 0;
  tmp[t] = v;
  __syncthreads();
  for (int off = 1; off < 256; off <<= 1) {
    int add = (t >= off) ? tmp[t - off] : 0;
    __syncthreads();
    tmp[t] += add;
    __syncthreads();
  }
  if (t < nb) blocksums[t] = tmp[t] - v;  // exclusive
  if (t == 0) row_start[n] = tmp[255];    // == E
}

__global__ void scan_p3_kernel(const int* __restrict__ counts, int n,
                               const int* __restrict__ blocksums,
                               int* __restrict__ row_start) {
  __shared__ int tmp[256];
  int t = threadIdx.x;
  int i = blockIdx.x * 256 + t;
  int v = (i < n) ? counts[i] : 0;
  tmp[t] = v;
  __syncthreads();
  for (int off = 1; off < 256; off <<= 1) {
    int add = (t >= off) ? tmp[t - off] : 0;
    __syncthreads();
    tmp[t] += add;
    __syncthreads();
  }
  if (i < n) row_start[i] = blocksums[blockIdx.x] + tmp[t] - v;
}

// fill CSR: per edge, slot under its dst; entry packs {src | seg<<17, bits(x)}
// (also re-zeroes cursor usage: cursor array is counts, zeroed by caller pass)
__global__ void zero_kernel(int* __restrict__ p, int n) {
  int i = blockIdx.x * blockDim.x + threadIdx.x;
  if (i < n) p[i] = 0;
}

__global__ void fill_kernel(const int* __restrict__ srcA, const int* __restrict__ dstA,
                            const float* __restrict__ eattr, int E,
                            const int* __restrict__ row_start, int* __restrict__ cursor,
                            const float* __restrict__ knotsE, int2* __restrict__ csr) {
  __shared__ float s_kx[128];
  if (threadIdx.x < 128) s_kx[threadIdx.x] = knotsE[threadIdx.x];
  __syncthreads();
  int i = blockIdx.x * blockDim.x + threadIdx.x;
  if (i >= E) return;
  int s = srcA[i], d = dstA[i];
  float x = eattr[i];
  int lo = 0, hi = 128;
  while (lo < hi) { int mid = (lo + hi) >> 1; if (s_kx[mid] < x) lo = mid + 1; else hi = mid; }
  int pos = row_start[d] + atomicAdd(&cursor[d], 1);
  csr[pos] = make_int2(s | (lo << 17), __float_as_int(x));
}

// ---------------------------------------------------------------------------
// Fused layer, 8 waves x 2 nodes.  Phase 1: wave stages its 2 nodes' CSR
// range into LDS, processes edges in PAIRS (lanes 0-31 edge A, 32-63 edge B,
// 16B/lane).  Phase 2: 16x256 @ 256x256 MFMA, wave owns 32 cols.
// Last layer: fused output head.
// ---------------------------------------------------------------------------
#define PAIR_FETCH(k)                                                              \
  int si##k = p + 2 * (k) + half; si##k = (si##k < hi) ? si##k : hi - 1;           \
  int2 e##k = ec[si##k];                                                           \
  ushort8v hv##k = *(const ushort8v*)(hbf + (size_t)(e##k.x & 0x1FFFF) * 256 + dl);

#define PAIR_COMP(k) {                                                             \
    float mk = (p + 2 * (k) + half < hi) ? 1.0f : 0.0f;                            \
    float xk = __int_as_float(e##k.y);                                             \
    int gk = e##k.x >> 17;                                                         \
    if (__builtin_expect(__ballot(gk != segN && gk != segP) != 0ull, 0)) {         \
      uint4v ab0 = *(const uint4v*)(AB + (size_t)gk * 256 + dl);                   \
      uint4v ab1 = *(const uint4v*)(AB + (size_t)gk * 256 + dl + 4);               \
      _Pragma("unroll") for (int j = 0; j < 8; ++j) {                              \
        unsigned abj = (j < 4) ? ab0[j] : ab1[j - 4];                              \
        float Ae = __uint_as_float(abj << 16);                                     \
        float Be = __uint_as_float(abj & 0xFFFF0000u);                             \
        float tt = bf2f(hv##k[j]) + fmaf(Ae, xk, Be);                              \
        acc[j] = fmaf(mk, fmaxf(tt, 0.0f), acc[j]);                                \
      }                                                                            \
    } else {                                                                       \
      bool isN = (gk == segN);                                                     \
      _Pragma("unroll") for (int j = 0; j < 8; ++j) {                              \
        float Ae = isN ? An[j] : Ap[j];                                            \
        float Be = isN ? Bn[j] : Bp[j];                                            \
        float tt = bf2f(hv##k[j]) + fmaf(Ae, xk, Be);                              \
        acc[j] = fmaf(mk, fmaxf(tt, 0.0f), acc[j]);                                \
      }                                                                            \
    }                                                                              \
  }

__global__ __launch_bounds__(512, 6) void layer_kernel(
    const u16* __restrict__ hbf, const int2* __restrict__ csr,
    const int* __restrict__ rowSt,
    const unsigned* __restrict__ AB, const int* __restrict__ segsel,
    const short* __restrict__ WT, const float* __restrict__ bias,
    u16* __restrict__ houtbf, float* __restrict__ outp,
    const float* __restrict__ ow3, const float* __restrict__ ob3, int N) {
  __shared__ u16 As[16][264];
  __shared__ int2 ecache[8][128];
  __shared__ float sw[768];
  __shared__ float sh[8][16][3];
  int wv = threadIdx.x >> 6, lane = threadIdx.x & 63;
  int nbase = blockIdx.x * 16;
  int d0 = lane * 4;
  int v0 = nbase + wv * 2;
  int half = lane >> 5;
  int dl = (lane & 31) * 8;

  if (outp) {  // preload head weights (block-uniform branch)
    for (int i = threadIdx.x; i < 768; i += 512) sw[i] = ow3[i];
  }

  int segN = segsel[0], segP = segsel[1];
  // pre-unpack (A,B) for the two live segments, 8 dims per lane (dl..dl+7)
  f32x8 An, Bn, Ap, Bp;
  {
    uint4v n0 = *(const uint4v*)(AB + (size_t)segN * 256 + dl);
    uint4v n1 = *(const uint4v*)(AB + (size_t)segN * 256 + dl + 4);
    uint4v p0v = *(const uint4v*)(AB + (size_t)segP * 256 + dl);
    uint4v p1v = *(const uint4v*)(AB + (size_t)segP * 256 + dl + 4);
#pragma unroll
    for (int j = 0; j < 8; ++j) {
      unsigned nj = (j < 4) ? n0[j] : n1[j - 4];
      unsigned pj = (j < 4) ? p0v[j] : p1v[j - 4];
      An[j] = __uint_as_float(nj << 16);
      Bn[j] = __uint_as_float(nj & 0xFFFF0000u);
      Ap[j] = __uint_as_float(pj << 16);
      Bp[j] = __uint_as_float(pj & 0xFFFF0000u);
    }
  }

  int rv0 = rowSt[v0], rv1 = rowSt[v0 + 1], rv2 = rowSt[v0 + 2];
  int range = rv2 - rv0;
  const int2* ec = &ecache[wv][0];

  if (__builtin_expect(range <= 128, 1)) {
    // stage the wave's whole edge range into LDS (coalesced, wave-local)
    for (int s = lane; s < range; s += 64) ecache[wv][s] = csr[(size_t)rv0 + s];
    for (int i = 0; i < 2; ++i) {
      int v = v0 + i;
      int lo = ((i == 0) ? rv0 : rv1) - rv0;
      int hi = ((i == 0) ? rv1 : rv2) - rv0;
      int deg = hi - lo;
      ushort8v sv = *(const ushort8v*)(hbf + (size_t)v * 256 + dl);
      float de = (float)deg * EPS_F;
      f32x8 acc = {0.f, 0.f, 0.f, 0.f, 0.f, 0.f, 0.f, 0.f};
      for (int p = lo; p < hi; p += 8) {  // 4 pairs = 8 edges per iteration
        PAIR_FETCH(0); PAIR_FETCH(1); PAIR_FETCH(2); PAIR_FETCH(3);
        PAIR_COMP(0); PAIR_COMP(1); PAIR_COMP(2); PAIR_COMP(3);
      }
      ushort8v ob;
#pragma unroll
      for (int j = 0; j < 8; ++j) {
        float tot = acc[j] + __shfl_xor(acc[j], 32);
        ob[j] = (u16)f2bf(bf2f(sv[j]) + de + tot);
      }
      if (half == 0) *(ushort8v*)&As[wv * 2 + i][dl] = ob;
    }
  } else {
    // rare fallback: direct 1-wide loop from global csr (4-dims/lane form)
    for (int i = 0; i < 2; ++i) {
      int v = v0 + i;
      int lo = (i == 0) ? rv0 : rv1;
      int hi = (i == 0) ? rv1 : rv2;
      int deg = hi - lo;
      ushort4v sv = *(const ushort4v*)(hbf + (size_t)v * 256 + d0);
      float de = (float)deg * EPS_F;
      f32x4 acc;
      acc.x = bf2f(sv.x) + de; acc.y = bf2f(sv.y) + de;
      acc.z = bf2f(sv.z) + de; acc.w = bf2f(sv.w) + de;
      for (int p = lo; p < hi; ++p) {
        int2 e = csr[(size_t)p];
        ushort4v hv = *(const ushort4v*)(hbf + (size_t)(e.x & 0x1FFFF) * 256 + d0);
        float x = __int_as_float(e.y);
        int g = __builtin_amdgcn_readfirstlane(e.x) >> 17;
        f32x4 Ae, Be;
        uint4v ab = *(const uint4v*)(AB + (size_t)g * 256 + d0);
#pragma unroll
        for (int j = 0; j < 4; ++j) {
          Ae[j] = __uint_as_float(ab[j] << 16);
          Be[j] = __uint_as_float(ab[j] & 0xFFFF0000u);
        }
#pragma unroll
        for (int j = 0; j < 4; ++j)
          acc[j] += fmaxf(bf2f(hv[j]) + fmaf(Ae[j], x, Be[j]), 0.0f);
      }
      ushort4v ob;
      ob.x = (u16)f2bf(acc.x); ob.y = (u16)f2bf(acc.y);
      ob.z = (u16)f2bf(acc.z); ob.w = (u16)f2bf(acc.w);
      *(ushort4v*)&As[wv * 2 + i][d0] = ob;
    }
  }
  __syncthreads();

  // ---- phase 2: [16,256] @ [256,256], wave owns 32 cols ----
  int colb = lane & 15, rowf = lane & 15, kgrp = (lane >> 4) * 8;
  int c0 = wv * 32;
  const short* wtc = WT + (size_t)(c0 + colb) * 256;
  const u16* Ar = &As[rowf][0];
  f32x4 acc0 = {0.f, 0.f, 0.f, 0.f}, acc1 = acc0;
  short8 b0 = *(const short8*)(wtc + kgrp);
  short8 b1 = *(const short8*)(wtc + 4096 + kgrp);
#pragma unroll
  for (int kt = 0; kt < 8; ++kt) {
    int k0 = kt * 32 + kgrp;
    short8 af = *(const short8*)(Ar + k0);
    short8 n0, n1;
    if (kt < 7) {
      int kn = k0 + 32;
      n0 = *(const short8*)(wtc + kn);
      n1 = *(const short8*)(wtc + 4096 + kn);
    }
    acc0 = __builtin_amdgcn_mfma_f32_16x16x32_bf16(af, b0, acc0, 0, 0, 0);
    acc1 = __builtin_amdgcn_mfma_f32_16x16x32_bf16(af, b1, acc1, 0, 0, 0);
    if (kt < 7) { b0 = n0; b1 = n1; }
  }
  int rbase = (lane >> 4) * 4;
  if (houtbf) {
#pragma unroll
    for (int nbk = 0; nbk < 2; ++nbk) {
      f32x4 a = (nbk == 0) ? acc0 : acc1;
      int col = c0 + nbk * 16 + colb;
      float bv = bias[col];
#pragma unroll
      for (int rr = 0; rr < 4; ++rr) {
        int vv = nbase + rbase + rr;
        if (vv < N) houtbf[(size_t)vv * 256 + col] = (u16)f2bf(a[rr] + bv);
      }
    }
  }
  if (outp) {  // fused head: project 16x256 block result to 16x3
    float p[4][3];
#pragma unroll
    for (int rr = 0; rr < 4; ++rr) {
      p[rr][0] = 0.f; p[rr][1] = 0.f; p[rr][2] = 0.f;
    }
#pragma unroll
    for (int nbk = 0; nbk < 2; ++nbk) {
      f32x4 a = (nbk == 0) ? acc0 : acc1;
      int col = c0 + nbk * 16 + colb;
      float bv = bias[col];
#pragma unroll
      for (int rr = 0; rr < 4; ++rr) {
        float val = a[rr] + bv;
#pragma unroll
        for (int o = 0; o < 3; ++o) p[rr][o] = fmaf(val, sw[col * 3 + o], p[rr][o]);
      }
    }
#pragma unroll
    for (int rr = 0; rr < 4; ++rr)
#pragma unroll
      for (int o = 0; o < 3; ++o) {
        float s = p[rr][o];
        s += __shfl_xor(s, 1, 16);
        s += __shfl_xor(s, 2, 16);
        s += __shfl_xor(s, 4, 16);
        s += __shfl_xor(s, 8, 16);
        if (colb == 0) sh[wv][rbase + rr][o] = s;
      }
    __syncthreads();
    int t = threadIdx.x;
    if (t < 48) {
      int row = t / 3, o = t % 3;
      float s = ob3[o];
#pragma unroll
      for (int w = 0; w < 8; ++w) s += sh[w][row][o];
      int vv = nbase + row;
      if (vv < N) outp[(size_t)vv * 3 + o] = s;
    }
  }
}

// ---------------------------------------------------------------------------
extern "C" void kernel_launch(void* const* d_in, const int* in_sizes, int n_in,
                              void* d_out, int out_size, void* d_ws, size_t ws_size,
                              hipStream_t stream) {
  const float* x     = (const float*)d_in[0];
  const float* eattr = (const float*)d_in[1];
  const int*   eidx  = (const int*)d_in[2];
  const float* nw1 = (const float*)d_in[3];
  const float* nb1 = (const float*)d_in[4];
  const float* nw2 = (const float*)d_in[5];
  const float* nb2 = (const float*)d_in[6];
  const float* ew1 = (const float*)d_in[7];
  const float* eb1 = (const float*)d_in[8];
  const float* ew2 = (const float*)d_in[9];
  const float* eb2 = (const float*)d_in[10];
  const float* gw  = (const float*)d_in[11];
  const float* gb  = (const float*)d_in[12];
  const float* ow  = (const float*)d_in[13];
  const float* ob  = (const float*)d_in[14];

  int N = in_sizes[0];
  int E = in_sizes[1];
  const int* srcA = eidx;
  const int* dstA = eidx + E;

  char* ws = (char*)d_ws;
  auto al = [](size_t v) { return (v + 255) & ~(size_t)255; };
  size_t off = 0;
  u16* hbfA    = (u16*)(ws + off);   off = al(off + (size_t)N * 256 * 2);
  u16* hbfB    = (u16*)(ws + off);   off = al(off + (size_t)N * 256 * 2);
  short* WT    = (short*)(ws + off); off = al(off + (size_t)4 * 256 * 256 * 2);
  float* knN   = (float*)(ws + off); off = al(off + 128 * 4);
  float* AN    = (float*)(ws + off); off = al(off + 129 * 256 * 4);
  float* BN    = (float*)(ws + off); off = al(off + 129 * 256 * 4);
  float* knE   = (float*)(ws + off); off = al(off + 128 * 4);
  unsigned* ABE = (unsigned*)(ws + off); off = al(off + 129 * 256 * 4);
  int* rankN   = (int*)(ws + off);   off = al(off + 128 * 4);
  int* act0N   = (int*)(ws + off);   off = al(off + 128 * 4);
  int* rankE   = (int*)(ws + off);   off = al(off + 128 * 4);
  int* act0E   = (int*)(ws + off);   off = al(off + 128 * 4);
  int* segselE = (int*)(ws + off);   off = al(off + 2 * 4);
  int* rowSt   = (int*)(ws + off);   off = al(off + (size_t)(N + 1) * 4);
  int* counts  = (int*)(ws + off);   off = al(off + (size_t)N * 4);
  int* bsums   = (int*)(ws + off);   off = al(off + 256 * 4);
  int2* csr    = (int2*)(ws + off);  off = al(off + (size_t)E * 8);
  (void)ws_size; (void)n_in; (void)out_size;

  int gN = (N + 255) / 256, gE = (E + 255) / 256;
  int gEnc = (N + 15) / 16;

  // encoder tables (merged builds)
  build_meta2_kernel<<<2, 128, 0, stream>>>(nw1, nb1, ew1, eb1, knN, rankN, act0N,
                                            knE, rankE, act0E, segselE);
  build_seg2_kernel<<<258, 256, 0, stream>>>(nw1, nb1, nw2, nb2, ew1, eb1, ew2, eb2,
                                             rankN, act0N, rankE, act0E, AN, BN, ABE);

  // node encoder + counts zero + weight convert (one dispatch)
  enc_fused_kernel<<<gEnc + gN + 1024, 256, 0, stream>>>(x, N, gEnc, gN, knN, AN, BN,
                                                         hbfA, counts, gw, WT);

  // CSR build
  hist_kernel<<<gE, 256, 0, stream>>>(dstA, E, counts);
  scan_p1_kernel<<<gN, 256, 0, stream>>>(counts, N, bsums);
  scan_p2_kernel<<<1, 256, 0, stream>>>(bsums, gN, rowSt, N);
  scan_p3_kernel<<<gN, 256, 0, stream>>>(counts, N, bsums, rowSt);
  zero_kernel<<<gN, 256, 0, stream>>>(counts, N);
  fill_kernel<<<gE, 256, 0, stream>>>(srcA, dstA, eattr, E, rowSt, counts, knE, csr);

  // fused layers (last layer also applies the output head)
  u16* hbc = hbfA;
  u16* hbn = hbfB;
  int gLayer = (N + 15) / 16;
  for (int l = 0; l < 4; ++l) {
    u16* hbo = (l == 3) ? nullptr : hbn;
    float* op = (l == 3) ? (float*)d_out : nullptr;
    layer_kernel<<<gLayer, 512, 0, stream>>>(hbc, csr, rowSt, ABE, segselE,
                                             WT + (size_t)l * 256 * 256,
                                             gb + (size_t)l * 256, hbo, op, ow, ob, N);
    u16* t = hbc; hbc = hbn; hbn = t;
  }
}

// Round 12
// 320.466 us; speedup vs baseline: 1.7917x; 1.7917x over previous
//
#include <hip/hip_runtime.h>
#include <stdint.h>

#define EPS_F 1e-7f

typedef float f32x4 __attribute__((ext_vector_type(4)));
typedef float f32x8 __attribute__((ext_vector_type(8)));
typedef short short8 __attribute__((ext_vector_type(8)));
typedef unsigned short u16;
typedef unsigned short ushort4v __attribute__((ext_vector_type(4)));
typedef unsigned short ushort8v __attribute__((ext_vector_type(8)));
typedef unsigned int uint4v __attribute__((ext_vector_type(4)));

__device__ __forceinline__ short f2bf(float f) {
  unsigned u = __float_as_uint(f);
  unsigned r = u + 0x7FFFu + ((u >> 16) & 1u);
  return (short)(r >> 16);
}
__device__ __forceinline__ float bf2f(u16 u) {
  return __uint_as_float((unsigned)u << 16);
}

// ---------------------------------------------------------------------------
// Encoder tables:  f(x) = relu(x*w1 + b1) @ W2 + b2  (scalar x -> R^256)
// 129 segments with knots at -b1_j/w1_j.  segsel: segment ids for x=-1, x=+1.
// Merged: block 0 = node encoder, block 1 = edge encoder (+segsel).
// ---------------------------------------------------------------------------
__global__ void build_meta2_kernel(const float* __restrict__ nw1, const float* __restrict__ nb1,
                                   const float* __restrict__ ew1, const float* __restrict__ eb1,
                                   float* __restrict__ knN, int* __restrict__ rankN,
                                   int* __restrict__ act0N,
                                   float* __restrict__ knE, int* __restrict__ rankE,
                                   int* __restrict__ act0E, int* __restrict__ segsel) {
  __shared__ float s_kx[128];
  __shared__ float s_sorted[128];
  int isE = blockIdx.x;
  const float* w1 = isE ? ew1 : nw1;
  const float* b1 = isE ? eb1 : nb1;
  float* knots = isE ? knE : knN;
  int* jrank = isE ? rankE : rankN;
  int* act0 = isE ? act0E : act0N;
  int t = threadIdx.x;  // 0..127
  float w = w1[t], b = b1[t];
  float kx = (w != 0.0f) ? (-b / w) : 3.4e38f;
  s_kx[t] = kx;
  int a0 = (w < 0.0f) || (w == 0.0f && b > 0.0f);  // active at x = -inf
  __syncthreads();
  int r = 0;
  for (int i = 0; i < 128; ++i) {
    float o = s_kx[i];
    if (o < kx || (o == kx && i < t)) ++r;
  }
  jrank[t] = r;
  act0[t] = a0;
  knots[r] = kx;
  s_sorted[r] = kx;
  __syncthreads();
  if (t == 0 && isE) {
    int lo = 0, hi = 128;
    while (lo < hi) { int m = (lo + hi) >> 1; if (s_sorted[m] < -1.0f) lo = m + 1; else hi = m; }
    segsel[0] = lo;
    lo = 0; hi = 128;
    while (lo < hi) { int m = (lo + hi) >> 1; if (s_sorted[m] < 1.0f) lo = m + 1; else hi = m; }
    segsel[1] = lo;
  }
}

// per-segment coefficients, both encoders: blocks 0..128 = node, 129..257 = edge
__global__ void build_seg2_kernel(const float* __restrict__ nw1, const float* __restrict__ nb1,
                                  const float* __restrict__ nw2, const float* __restrict__ nb2,
                                  const float* __restrict__ ew1, const float* __restrict__ eb1,
                                  const float* __restrict__ ew2, const float* __restrict__ eb2,
                                  const int* __restrict__ rankN, const int* __restrict__ act0N,
                                  const int* __restrict__ rankE, const int* __restrict__ act0E,
                                  float* __restrict__ AN, float* __restrict__ BN,
                                  unsigned* __restrict__ ABE) {
  int isE = (blockIdx.x >= 129);
  int s = isE ? (blockIdx.x - 129) : blockIdx.x;  // 0..128
  int t = threadIdx.x;                            // 0..255
  const float* w1 = isE ? ew1 : nw1;
  const float* b1 = isE ? eb1 : nb1;
  const float* w2 = isE ? ew2 : nw2;
  const float* b2 = isE ? eb2 : nb2;
  const int* jrank = isE ? rankE : rankN;
  const int* act0 = isE ? act0E : act0N;
  __shared__ float s_w1[128], s_b1[128];
  __shared__ int s_on[128];
  if (t < 128) {
    s_w1[t] = w1[t];
    s_b1[t] = b1[t];
    s_on[t] = act0[t] ^ (jrank[t] < s ? 1 : 0);
  }
  __syncthreads();
  float A = 0.0f, B = b2[t];
#pragma unroll 4
  for (int j = 0; j < 128; ++j) {
    if (s_on[j]) {
      float w2v = w2[j * 256 + t];
      A = fmaf(s_w1[j], w2v, A);
      B = fmaf(s_b1[j], w2v, B);
    }
  }
  if (!isE) {
    AN[s * 256 + t] = A;
    BN[s * 256 + t] = B;
  } else {
    unsigned a = (unsigned)(u16)f2bf(A);
    unsigned bb = (unsigned)(u16)f2bf(B);
    ABE[s * 256 + t] = a | (bb << 16);
  }
}

// fused: node encoder (blocks [0,gEnc)), counts zero ([gEnc,gEnc+gZero)),
// weight convert ([gEnc+gZero, +1024))
__global__ void enc_fused_kernel(const float* __restrict__ in, int nrows, int gEnc, int gZero,
                                 const float* __restrict__ knots, const float* __restrict__ segA,
                                 const float* __restrict__ segB, u16* __restrict__ outbf,
                                 int* __restrict__ counts,
                                 const float* __restrict__ W, short* __restrict__ WT) {
  int bid = blockIdx.x;
  int t = threadIdx.x;
  if (bid < gEnc) {
    __shared__ float s_kx[128];
    if (t < 128) s_kx[t] = knots[t];
    __syncthreads();
    int r0 = bid * 16;
    int rEnd = r0 + 16;
    if (rEnd > nrows) rEnd = nrows;
    for (int r = r0; r < rEnd; ++r) {
      float x = in[r];
      int lo = 0, hi = 128;
      while (lo < hi) { int mid = (lo + hi) >> 1; if (s_kx[mid] < x) lo = mid + 1; else hi = mid; }
      outbf[(size_t)r * 256 + t] = (u16)f2bf(fmaf(segA[lo * 256 + t], x, segB[lo * 256 + t]));
    }
  } else if (bid < gEnc + gZero) {
    int i = (bid - gEnc) * 256 + t;
    if (i < nrows) counts[i] = 0;
  } else {
    int cb = bid - gEnc - gZero;           // 0..1023
    int l = cb >> 8, nn = cb & 255, k = t; // gnn_w [4][256][256] -> WT [4][256][256]^T
    WT[((size_t)l * 256 + nn) * 256 + k] = f2bf(W[((size_t)l * 256 + k) * 256 + nn]);
  }
}

__global__ void hist_kernel(const int* __restrict__ dst, int E, int* __restrict__ counts) {
  int i = blockIdx.x * blockDim.x + threadIdx.x;
  if (i < E) atomicAdd(&counts[dst[i]], 1);
}

// 3-phase exclusive scan of counts[0..n) -> row_start[0..n], row_start[n]=E
__global__ void scan_p1_kernel(const int* __restrict__ counts, int n,
                               int* __restrict__ blocksums) {
  __shared__ int tmp[256];
  int t = threadIdx.x;
  int i = blockIdx.x * 256 + t;
  tmp[t] = (i < n) ? counts[i] : 0;
  __syncthreads();
  for (int off = 128; off > 0; off >>= 1) {
    if (t < off) tmp[t] += tmp[t + off];
    __syncthreads();
  }
  if (t == 0) blocksums[blockIdx.x] = tmp[0];
}

__global__ void scan_p2_kernel(int* __restrict__ blocksums, int nb,
                               int* __restrict__ row_start, int n) {
  __shared__ int tmp[256];
  int t = threadIdx.x;
  int v = (t < nb) ? blocksums[t] : 0;
  tmp[t] = v;
  __syncthreads();
  for (int off = 1; off < 256; off <<= 1) {
    int add = (t >= off) ? tmp[t - off] : 0;
    __syncthreads();
    tmp[t] += add;
    __syncthreads();
  }
  if (t < nb) blocksums[t] = tmp[t] - v;  // exclusive
  if (t == 0) row_start[n] = tmp[255];    // == E
}

__global__ void scan_p3_kernel(const int* __restrict__ counts, int n,
                               const int* __restrict__ blocksums,
                               int* __restrict__ row_start) {
  __shared__ int tmp[256];
  int t = threadIdx.x;
  int i = blockIdx.x * 256 + t;
  int v = (i < n) ? counts[i] : 0;
  tmp[t] = v;
  __syncthreads();
  for (int off = 1; off < 256; off <<= 1) {
    int add = (t >= off) ? tmp[t - off] : 0;
    __syncthreads();
    tmp[t] += add;
    __syncthreads();
  }
  if (i < n) row_start[i] = blocksums[blockIdx.x] + tmp[t] - v;
}

__global__ void zero_kernel(int* __restrict__ p, int n) {
  int i = blockIdx.x * blockDim.x + threadIdx.x;
  if (i < n) p[i] = 0;
}

// fill CSR: per edge, slot under its dst; entry packs {src | seg<<17, bits(x)}
__global__ void fill_kernel(const int* __restrict__ srcA, const int* __restrict__ dstA,
                            const float* __restrict__ eattr, int E,
                            const int* __restrict__ row_start, int* __restrict__ cursor,
                            const float* __restrict__ knotsE, int2* __restrict__ csr) {
  __shared__ float s_kx[128];
  if (threadIdx.x < 128) s_kx[threadIdx.x] = knotsE[threadIdx.x];
  __syncthreads();
  int i = blockIdx.x * blockDim.x + threadIdx.x;
  if (i >= E) return;
  int s = srcA[i], d = dstA[i];
  float x = eattr[i];
  int lo = 0, hi = 128;
  while (lo < hi) { int mid = (lo + hi) >> 1; if (s_kx[mid] < x) lo = mid + 1; else hi = mid; }
  int pos = row_start[d] + atomicAdd(&cursor[d], 1);
  csr[pos] = make_int2(s | (lo << 17), __float_as_int(x));
}

// ---------------------------------------------------------------------------
// Fused layer (r10 measured-good config).  Phase 1: wave stages its 4 nodes'
// CSR range into LDS, processes edges in PAIRS (lanes 0-31 edge A, 32-63
// edge B, 16B/lane) -- one wave-wide vmem instruction covers 2 edges.
// Accumulator f32x8/lane, folded across halves at node end via shfl_xor(32).
// Phase 2: 16x256 @ 256x256 MFMA.  Last layer: fused output head.
// NOTE: launch_bounds(256,2) -- do NOT raise min-waves: r11 showed the
// register cap forces per-edge scratch spill (WRITE_SIZE 15->127 MB, 2x dur).
// ---------------------------------------------------------------------------
#define PAIR_FETCH(k)                                                              \
  int si##k = p + 2 * (k) + half; si##k = (si##k < hi) ? si##k : hi - 1;           \
  int2 e##k = ec[si##k];                                                           \
  ushort8v hv##k = *(const ushort8v*)(hbf + (size_t)(e##k.x & 0x1FFFF) * 256 + dl);

#define PAIR_COMP(k) {                                                             \
    float mk = (p + 2 * (k) + half < hi) ? 1.0f : 0.0f;                            \
    float xk = __int_as_float(e##k.y);                                             \
    int gk = e##k.x >> 17;                                                         \
    if (__builtin_expect(__ballot(gk != segN && gk != segP) != 0ull, 0)) {         \
      uint4v ab0 = *(const uint4v*)(AB + (size_t)gk * 256 + dl);                   \
      uint4v ab1 = *(const uint4v*)(AB + (size_t)gk * 256 + dl + 4);               \
      _Pragma("unroll") for (int j = 0; j < 8; ++j) {                              \
        unsigned abj = (j < 4) ? ab0[j] : ab1[j - 4];                              \
        float Ae = __uint_as_float(abj << 16);                                     \
        float Be = __uint_as_float(abj & 0xFFFF0000u);                             \
        float tt = bf2f(hv##k[j]) + fmaf(Ae, xk, Be);                              \
        acc[j] = fmaf(mk, fmaxf(tt, 0.0f), acc[j]);                                \
      }                                                                            \
    } else {                                                                       \
      bool isN = (gk == segN);                                                     \
      _Pragma("unroll") for (int j = 0; j < 8; ++j) {                              \
        float Ae = isN ? An[j] : Ap[j];                                            \
        float Be = isN ? Bn[j] : Bp[j];                                            \
        float tt = bf2f(hv##k[j]) + fmaf(Ae, xk, Be);                              \
        acc[j] = fmaf(mk, fmaxf(tt, 0.0f), acc[j]);                                \
      }                                                                            \
    }                                                                              \
  }

__global__ __launch_bounds__(256, 2) void layer_kernel(
    const u16* __restrict__ hbf, const int2* __restrict__ csr,
    const int* __restrict__ rowSt,
    const unsigned* __restrict__ AB, const int* __restrict__ segsel,
    const short* __restrict__ WT, const float* __restrict__ bias,
    u16* __restrict__ houtbf, float* __restrict__ outp,
    const float* __restrict__ ow3, const float* __restrict__ ob3, int N) {
  __shared__ u16 As[16][264];
  __shared__ int2 ecache[4][256];
  __shared__ float sw[768];
  __shared__ float sh[4][16][3];
  int wv = threadIdx.x >> 6, lane = threadIdx.x & 63;
  int nbase = blockIdx.x * 16;
  int d0 = lane * 4;
  int v0 = nbase + wv * 4;
  int half = lane >> 5;
  int dl = (lane & 31) * 8;

  if (outp) {  // preload head weights (block-uniform branch)
    for (int i = threadIdx.x; i < 768; i += 256) sw[i] = ow3[i];
  }

  int segN = segsel[0], segP = segsel[1];
  // pre-unpack (A,B) for the two live segments, 8 dims per lane (dl..dl+7)
  f32x8 An, Bn, Ap, Bp;
  {
    uint4v n0 = *(const uint4v*)(AB + (size_t)segN * 256 + dl);
    uint4v n1 = *(const uint4v*)(AB + (size_t)segN * 256 + dl + 4);
    uint4v p0v = *(const uint4v*)(AB + (size_t)segP * 256 + dl);
    uint4v p1v = *(const uint4v*)(AB + (size_t)segP * 256 + dl + 4);
#pragma unroll
    for (int j = 0; j < 8; ++j) {
      unsigned nj = (j < 4) ? n0[j] : n1[j - 4];
      unsigned pj = (j < 4) ? p0v[j] : p1v[j - 4];
      An[j] = __uint_as_float(nj << 16);
      Bn[j] = __uint_as_float(nj & 0xFFFF0000u);
      Ap[j] = __uint_as_float(pj << 16);
      Bp[j] = __uint_as_float(pj & 0xFFFF0000u);
    }
  }

  int rv0 = rowSt[v0], rv1 = rowSt[v0 + 1], rv2 = rowSt[v0 + 2];
  int rv3 = rowSt[v0 + 3], rv4 = rowSt[v0 + 4];
  int range = rv4 - rv0;
  const int2* ec = &ecache[wv][0];

  if (__builtin_expect(range <= 256, 1)) {
    // stage the wave's whole edge range into LDS (coalesced, wave-local)
    for (int s = lane; s < range; s += 64) ecache[wv][s] = csr[(size_t)rv0 + s];
    for (int i = 0; i < 4; ++i) {
      int v = v0 + i;
      int lo = ((i == 0) ? rv0 : (i == 1) ? rv1 : (i == 2) ? rv2 : rv3) - rv0;
      int hi = ((i == 0) ? rv1 : (i == 1) ? rv2 : (i == 2) ? rv3 : rv4) - rv0;
      int deg = hi - lo;
      ushort8v sv = *(const ushort8v*)(hbf + (size_t)v * 256 + dl);
      float de = (float)deg * EPS_F;
      f32x8 acc = {0.f, 0.f, 0.f, 0.f, 0.f, 0.f, 0.f, 0.f};
      for (int p = lo; p < hi; p += 8) {  // 4 pairs = 8 edges per iteration
        PAIR_FETCH(0); PAIR_FETCH(1); PAIR_FETCH(2); PAIR_FETCH(3);
        PAIR_COMP(0); PAIR_COMP(1); PAIR_COMP(2); PAIR_COMP(3);
      }
      ushort8v ob;
#pragma unroll
      for (int j = 0; j < 8; ++j) {
        float tot = acc[j] + __shfl_xor(acc[j], 32);
        ob[j] = (u16)f2bf(bf2f(sv[j]) + de + tot);
      }
      if (half == 0) *(ushort8v*)&As[wv * 4 + i][dl] = ob;
    }
  } else {
    // rare fallback: direct 1-wide loop from global csr (4-dims/lane form)
    for (int i = 0; i < 4; ++i) {
      int v = v0 + i;
      int lo = (i == 0) ? rv0 : (i == 1) ? rv1 : (i == 2) ? rv2 : rv3;
      int hi = (i == 0) ? rv1 : (i == 1) ? rv2 : (i == 2) ? rv3 : rv4;
      int deg = hi - lo;
      ushort4v sv = *(const ushort4v*)(hbf + (size_t)v * 256 + d0);
      float de = (float)deg * EPS_F;
      f32x4 acc;
      acc.x = bf2f(sv.x) + de; acc.y = bf2f(sv.y) + de;
      acc.z = bf2f(sv.z) + de; acc.w = bf2f(sv.w) + de;
      for (int p = lo; p < hi; ++p) {
        int2 e = csr[(size_t)p];
        ushort4v hv = *(const ushort4v*)(hbf + (size_t)(e.x & 0x1FFFF) * 256 + d0);
        float x = __int_as_float(e.y);
        int g = __builtin_amdgcn_readfirstlane(e.x) >> 17;
        f32x4 Ae, Be;
        uint4v ab = *(const uint4v*)(AB + (size_t)g * 256 + d0);
#pragma unroll
        for (int j = 0; j < 4; ++j) {
          Ae[j] = __uint_as_float(ab[j] << 16);
          Be[j] = __uint_as_float(ab[j] & 0xFFFF0000u);
        }
#pragma unroll
        for (int j = 0; j < 4; ++j)
          acc[j] += fmaxf(bf2f(hv[j]) + fmaf(Ae[j], x, Be[j]), 0.0f);
      }
      ushort4v ob;
      ob.x = (u16)f2bf(acc.x); ob.y = (u16)f2bf(acc.y);
      ob.z = (u16)f2bf(acc.z); ob.w = (u16)f2bf(acc.w);
      *(ushort4v*)&As[wv * 4 + i][d0] = ob;
    }
  }
  __syncthreads();

  // ---- phase 2: [16,256] @ [256,256] ----
  int colb = lane & 15, rowf = lane & 15, kgrp = (lane >> 4) * 8;
  int c0 = wv * 64;
  const short* wtc = WT + (size_t)(c0 + colb) * 256;
  const u16* Ar = &As[rowf][0];
  f32x4 acc0 = {0.f, 0.f, 0.f, 0.f}, acc1 = acc0, acc2 = acc0, acc3 = acc0;
  short8 b0 = *(const short8*)(wtc + kgrp);
  short8 b1 = *(const short8*)(wtc + 4096 + kgrp);
  short8 b2 = *(const short8*)(wtc + 8192 + kgrp);
  short8 b3 = *(const short8*)(wtc + 12288 + kgrp);
#pragma unroll
  for (int kt = 0; kt < 8; ++kt) {
    int k0 = kt * 32 + kgrp;
    short8 af = *(const short8*)(Ar + k0);
    short8 n0, n1, n2, n3;
    if (kt < 7) {
      int kn = k0 + 32;
      n0 = *(const short8*)(wtc + kn);
      n1 = *(const short8*)(wtc + 4096 + kn);
      n2 = *(const short8*)(wtc + 8192 + kn);
      n3 = *(const short8*)(wtc + 12288 + kn);
    }
    acc0 = __builtin_amdgcn_mfma_f32_16x16x32_bf16(af, b0, acc0, 0, 0, 0);
    acc1 = __builtin_amdgcn_mfma_f32_16x16x32_bf16(af, b1, acc1, 0, 0, 0);
    acc2 = __builtin_amdgcn_mfma_f32_16x16x32_bf16(af, b2, acc2, 0, 0, 0);
    acc3 = __builtin_amdgcn_mfma_f32_16x16x32_bf16(af, b3, acc3, 0, 0, 0);
    if (kt < 7) { b0 = n0; b1 = n1; b2 = n2; b3 = n3; }
  }
  int rbase = (lane >> 4) * 4;
  if (houtbf) {
#pragma unroll
    for (int nbk = 0; nbk < 4; ++nbk) {
      f32x4 a = (nbk == 0) ? acc0 : (nbk == 1) ? acc1 : (nbk == 2) ? acc2 : acc3;
      int col = c0 + nbk * 16 + colb;
      float bv = bias[col];
#pragma unroll
      for (int rr = 0; rr < 4; ++rr) {
        int vv = nbase + rbase + rr;
        if (vv < N) houtbf[(size_t)vv * 256 + col] = (u16)f2bf(a[rr] + bv);
      }
    }
  }
  if (outp) {  // fused head: project 16x256 block result to 16x3
    float p[4][3];
#pragma unroll
    for (int rr = 0; rr < 4; ++rr) {
      p[rr][0] = 0.f; p[rr][1] = 0.f; p[rr][2] = 0.f;
    }
#pragma unroll
    for (int nbk = 0; nbk < 4; ++nbk) {
      f32x4 a = (nbk == 0) ? acc0 : (nbk == 1) ? acc1 : (nbk == 2) ? acc2 : acc3;
      int col = c0 + nbk * 16 + colb;
      float bv = bias[col];
#pragma unroll
      for (int rr = 0; rr < 4; ++rr) {
        float val = a[rr] + bv;
#pragma unroll
        for (int o = 0; o < 3; ++o) p[rr][o] = fmaf(val, sw[col * 3 + o], p[rr][o]);
      }
    }
#pragma unroll
    for (int rr = 0; rr < 4; ++rr)
#pragma unroll
      for (int o = 0; o < 3; ++o) {
        float s = p[rr][o];
        s += __shfl_xor(s, 1, 16);
        s += __shfl_xor(s, 2, 16);
        s += __shfl_xor(s, 4, 16);
        s += __shfl_xor(s, 8, 16);
        if (colb == 0) sh[wv][rbase + rr][o] = s;
      }
    __syncthreads();
    int t = threadIdx.x;
    if (t < 48) {
      int row = t / 3, o = t % 3;
      float s = sh[0][row][o] + sh[1][row][o] + sh[2][row][o] + sh[3][row][o] + ob3[o];
      int vv = nbase + row;
      if (vv < N) outp[(size_t)vv * 3 + o] = s;
    }
  }
}

// ---------------------------------------------------------------------------
extern "C" void kernel_launch(void* const* d_in, const int* in_sizes, int n_in,
                              void* d_out, int out_size, void* d_ws, size_t ws_size,
                              hipStream_t stream) {
  const float* x     = (const float*)d_in[0];
  const float* eattr = (const float*)d_in[1];
  const int*   eidx  = (const int*)d_in[2];
  const float* nw1 = (const float*)d_in[3];
  const float* nb1 = (const float*)d_in[4];
  const float* nw2 = (const float*)d_in[5];
  const float* nb2 = (const float*)d_in[6];
  const float* ew1 = (const float*)d_in[7];
  const float* eb1 = (const float*)d_in[8];
  const float* ew2 = (const float*)d_in[9];
  const float* eb2 = (const float*)d_in[10];
  const float* gw  = (const float*)d_in[11];
  const float* gb  = (const float*)d_in[12];
  const float* ow  = (const float*)d_in[13];
  const float* ob  = (const float*)d_in[14];

  int N = in_sizes[0];
  int E = in_sizes[1];
  const int* srcA = eidx;
  const int* dstA = eidx + E;

  char* ws = (char*)d_ws;
  auto al = [](size_t v) { return (v + 255) & ~(size_t)255; };
  size_t off = 0;
  u16* hbfA    = (u16*)(ws + off);   off = al(off + (size_t)N * 256 * 2);
  u16* hbfB    = (u16*)(ws + off);   off = al(off + (size_t)N * 256 * 2);
  short* WT    = (short*)(ws + off); off = al(off + (size_t)4 * 256 * 256 * 2);
  float* knN   = (float*)(ws + off); off = al(off + 128 * 4);
  float* AN    = (float*)(ws + off); off = al(off + 129 * 256 * 4);
  float* BN    = (float*)(ws + off); off = al(off + 129 * 256 * 4);
  float* knE   = (float*)(ws + off); off = al(off + 128 * 4);
  unsigned* ABE = (unsigned*)(ws + off); off = al(off + 129 * 256 * 4);
  int* rankN   = (int*)(ws + off);   off = al(off + 128 * 4);
  int* act0N   = (int*)(ws + off);   off = al(off + 128 * 4);
  int* rankE   = (int*)(ws + off);   off = al(off + 128 * 4);
  int* act0E   = (int*)(ws + off);   off = al(off + 128 * 4);
  int* segselE = (int*)(ws + off);   off = al(off + 2 * 4);
  int* rowSt   = (int*)(ws + off);   off = al(off + (size_t)(N + 1) * 4);
  int* counts  = (int*)(ws + off);   off = al(off + (size_t)N * 4);
  int* bsums   = (int*)(ws + off);   off = al(off + 256 * 4);
  int2* csr    = (int2*)(ws + off);  off = al(off + (size_t)E * 8);
  (void)ws_size; (void)n_in; (void)out_size;

  int gN = (N + 255) / 256, gE = (E + 255) / 256;
  int gEnc = (N + 15) / 16;

  // encoder tables (merged builds)
  build_meta2_kernel<<<2, 128, 0, stream>>>(nw1, nb1, ew1, eb1, knN, rankN, act0N,
                                            knE, rankE, act0E, segselE);
  build_seg2_kernel<<<258, 256, 0, stream>>>(nw1, nb1, nw2, nb2, ew1, eb1, ew2, eb2,
                                             rankN, act0N, rankE, act0E, AN, BN, ABE);

  // node encoder + counts zero + weight convert (one dispatch)
  enc_fused_kernel<<<gEnc + gN + 1024, 256, 0, stream>>>(x, N, gEnc, gN, knN, AN, BN,
                                                         hbfA, counts, gw, WT);

  // CSR build
  hist_kernel<<<gE, 256, 0, stream>>>(dstA, E, counts);
  scan_p1_kernel<<<gN, 256, 0, stream>>>(counts, N, bsums);
  scan_p2_kernel<<<1, 256, 0, stream>>>(bsums, gN, rowSt, N);
  scan_p3_kernel<<<gN, 256, 0, stream>>>(counts, N, bsums, rowSt);
  zero_kernel<<<gN, 256, 0, stream>>>(counts, N);
  fill_kernel<<<gE, 256, 0, stream>>>(srcA, dstA, eattr, E, rowSt, counts, knE, csr);

  // fused layers (last layer also applies the output head)
  u16* hbc = hbfA;
  u16* hbn = hbfB;
  int gLayer = (N + 15) / 16;
  for (int l = 0; l < 4; ++l) {
    u16* hbo = (l == 3) ? nullptr : hbn;
    float* op = (l == 3) ? (float*)d_out : nullptr;
    layer_kernel<<<gLayer, 256, 0, stream>>>(hbc, csr, rowSt, ABE, segselE,
                                             WT + (size_t)l * 256 * 256,
                                             gb + (size_t)l * 256, hbo, op, ow, ob, N);
    u16* t = hbc; hbc = hbn; hbn = t;
  }
}

// Round 13
// 305.645 us; speedup vs baseline: 1.8786x; 1.0485x over previous
//
#include <hip/hip_runtime.h>
#include <stdint.h>

#define EPS_F 1e-7f

typedef float f32x4 __attribute__((ext_vector_type(4)));
typedef float f32x8 __attribute__((ext_vector_type(8)));
typedef short short8 __attribute__((ext_vector_type(8)));
typedef unsigned short u16;
typedef unsigned short ushort4v __attribute__((ext_vector_type(4)));
typedef unsigned short ushort8v __attribute__((ext_vector_type(8)));
typedef unsigned int uint4v __attribute__((ext_vector_type(4)));

__device__ __forceinline__ short f2bf(float f) {
  unsigned u = __float_as_uint(f);
  unsigned r = u + 0x7FFFu + ((u >> 16) & 1u);
  return (short)(r >> 16);
}
__device__ __forceinline__ float bf2f(u16 u) {
  return __uint_as_float((unsigned)u << 16);
}

// ---------------------------------------------------------------------------
// Encoder tables:  f(x) = relu(x*w1 + b1) @ W2 + b2  (scalar x -> R^256)
// 129 segments with knots at -b1_j/w1_j.
// segsel[0..1] = edge-table segments at x=-1,+1; segsel[2..3] = node-table.
// Merged: block 0 = node encoder, block 1 = edge encoder.
// ---------------------------------------------------------------------------
__global__ void build_meta2_kernel(const float* __restrict__ nw1, const float* __restrict__ nb1,
                                   const float* __restrict__ ew1, const float* __restrict__ eb1,
                                   float* __restrict__ knN, int* __restrict__ rankN,
                                   int* __restrict__ act0N,
                                   float* __restrict__ knE, int* __restrict__ rankE,
                                   int* __restrict__ act0E, int* __restrict__ segsel) {
  __shared__ float s_kx[128];
  __shared__ float s_sorted[128];
  int isE = blockIdx.x;
  const float* w1 = isE ? ew1 : nw1;
  const float* b1 = isE ? eb1 : nb1;
  float* knots = isE ? knE : knN;
  int* jrank = isE ? rankE : rankN;
  int* act0 = isE ? act0E : act0N;
  int t = threadIdx.x;  // 0..127
  float w = w1[t], b = b1[t];
  float kx = (w != 0.0f) ? (-b / w) : 3.4e38f;
  s_kx[t] = kx;
  int a0 = (w < 0.0f) || (w == 0.0f && b > 0.0f);  // active at x = -inf
  __syncthreads();
  int r = 0;
  for (int i = 0; i < 128; ++i) {
    float o = s_kx[i];
    if (o < kx || (o == kx && i < t)) ++r;
  }
  jrank[t] = r;
  act0[t] = a0;
  knots[r] = kx;
  s_sorted[r] = kx;
  __syncthreads();
  if (t == 0) {
    int base = isE ? 0 : 2;
    int lo = 0, hi = 128;
    while (lo < hi) { int m = (lo + hi) >> 1; if (s_sorted[m] < -1.0f) lo = m + 1; else hi = m; }
    segsel[base + 0] = lo;
    lo = 0; hi = 128;
    while (lo < hi) { int m = (lo + hi) >> 1; if (s_sorted[m] < 1.0f) lo = m + 1; else hi = m; }
    segsel[base + 1] = lo;
  }
}

// per-segment coefficients, both encoders: blocks 0..128 = node, 129..257 = edge
__global__ void build_seg2_kernel(const float* __restrict__ nw1, const float* __restrict__ nb1,
                                  const float* __restrict__ nw2, const float* __restrict__ nb2,
                                  const float* __restrict__ ew1, const float* __restrict__ eb1,
                                  const float* __restrict__ ew2, const float* __restrict__ eb2,
                                  const int* __restrict__ rankN, const int* __restrict__ act0N,
                                  const int* __restrict__ rankE, const int* __restrict__ act0E,
                                  float* __restrict__ AN, float* __restrict__ BN,
                                  unsigned* __restrict__ ABE) {
  int isE = (blockIdx.x >= 129);
  int s = isE ? (blockIdx.x - 129) : blockIdx.x;  // 0..128
  int t = threadIdx.x;                            // 0..255
  const float* w1 = isE ? ew1 : nw1;
  const float* b1 = isE ? eb1 : nb1;
  const float* w2 = isE ? ew2 : nw2;
  const float* b2 = isE ? eb2 : nb2;
  const int* jrank = isE ? rankE : rankN;
  const int* act0 = isE ? act0E : act0N;
  __shared__ float s_w1[128], s_b1[128];
  __shared__ int s_on[128];
  if (t < 128) {
    s_w1[t] = w1[t];
    s_b1[t] = b1[t];
    s_on[t] = act0[t] ^ (jrank[t] < s ? 1 : 0);
  }
  __syncthreads();
  float A = 0.0f, B = b2[t];
#pragma unroll 4
  for (int j = 0; j < 128; ++j) {
    if (s_on[j]) {
      float w2v = w2[j * 256 + t];
      A = fmaf(s_w1[j], w2v, A);
      B = fmaf(s_b1[j], w2v, B);
    }
  }
  if (!isE) {
    AN[s * 256 + t] = A;
    BN[s * 256 + t] = B;
  } else {
    unsigned a = (unsigned)(u16)f2bf(A);
    unsigned bb = (unsigned)(u16)f2bf(B);
    ABE[s * 256 + t] = a | (bb << 16);
  }
}

// fused prep: counts zero (blocks [0,gZero)) + weight convert ([gZero,+1024))
__global__ void prep_fused_kernel(int nrows, int gZero, int* __restrict__ counts,
                                  const float* __restrict__ W, short* __restrict__ WT) {
  int bid = blockIdx.x;
  int t = threadIdx.x;
  if (bid < gZero) {
    int i = bid * 256 + t;
    if (i < nrows) counts[i] = 0;
  } else {
    int cb = bid - gZero;                  // 0..1023
    int l = cb >> 8, nn = cb & 255, k = t; // gnn_w [4][256][256] -> WT transposed
    WT[((size_t)l * 256 + nn) * 256 + k] = f2bf(W[((size_t)l * 256 + k) * 256 + nn]);
  }
}

__global__ void hist_kernel(const int* __restrict__ dst, int E, int* __restrict__ counts) {
  int i = blockIdx.x * blockDim.x + threadIdx.x;
  if (i < E) atomicAdd(&counts[dst[i]], 1);
}

// 3-phase exclusive scan of counts[0..n) -> row_start[0..n], row_start[n]=E
__global__ void scan_p1_kernel(const int* __restrict__ counts, int n,
                               int* __restrict__ blocksums) {
  __shared__ int tmp[256];
  int t = threadIdx.x;
  int i = blockIdx.x * 256 + t;
  tmp[t] = (i < n) ? counts[i] : 0;
  __syncthreads();
  for (int off = 128; off > 0; off >>= 1) {
    if (t < off) tmp[t] += tmp[t + off];
    __syncthreads();
  }
  if (t == 0) blocksums[blockIdx.x] = tmp[0];
}

__global__ void scan_p2_kernel(int* __restrict__ blocksums, int nb,
                               int* __restrict__ row_start, int n) {
  __shared__ int tmp[256];
  int t = threadIdx.x;
  int v = (t < nb) ? blocksums[t] : 0;
  tmp[t] = v;
  __syncthreads();
  for (int off = 1; off < 256; off <<= 1) {
    int add = (t >= off) ? tmp[t - off] : 0;
    __syncthreads();
    tmp[t] += add;
    __syncthreads();
  }
  if (t < nb) blocksums[t] = tmp[t] - v;  // exclusive
  if (t == 0) row_start[n] = tmp[255];    // == E
}

__global__ void scan_p3_kernel(const int* __restrict__ counts, int n,
                               const int* __restrict__ blocksums,
                               int* __restrict__ row_start) {
  __shared__ int tmp[256];
  int t = threadIdx.x;
  int i = blockIdx.x * 256 + t;
  int v = (i < n) ? counts[i] : 0;
  tmp[t] = v;
  __syncthreads();
  for (int off = 1; off < 256; off <<= 1) {
    int add = (t >= off) ? tmp[t - off] : 0;
    __syncthreads();
    tmp[t] += add;
    __syncthreads();
  }
  if (i < n) row_start[i] = blocksums[blockIdx.x] + tmp[t] - v;
}

__global__ void zero_kernel(int* __restrict__ p, int n) {
  int i = blockIdx.x * blockDim.x + threadIdx.x;
  if (i < n) p[i] = 0;
}

// fill CSR: per edge, slot under its dst; entry packs {src | seg<<17, bits(x)}.
// Also stores x[src] per slot (xsrc) for the gather-free layer 0.
__global__ void fill_kernel(const int* __restrict__ srcA, const int* __restrict__ dstA,
                            const float* __restrict__ eattr, const float* __restrict__ xin,
                            int E, const int* __restrict__ row_start, int* __restrict__ cursor,
                            const float* __restrict__ knotsE, int2* __restrict__ csr,
                            float* __restrict__ xsrc) {
  __shared__ float s_kx[128];
  if (threadIdx.x < 128) s_kx[threadIdx.x] = knotsE[threadIdx.x];
  __syncthreads();
  int i = blockIdx.x * blockDim.x + threadIdx.x;
  if (i >= E) return;
  int s = srcA[i], d = dstA[i];
  float x = eattr[i];
  int lo = 0, hi = 128;
  while (lo < hi) { int mid = (lo + hi) >> 1; if (s_kx[mid] < x) lo = mid + 1; else hi = mid; }
  int pos = row_start[d] + atomicAdd(&cursor[d], 1);
  csr[pos] = make_int2(s | (lo << 17), __float_as_int(x));
  xsrc[pos] = xin[s];
}

// ---------------------------------------------------------------------------
// Layer 0 (gather-free): h[src] = node-table(x_src), 2 live segments (b1=0),
// so each 512B neighbor row is computed in registers from a 4B scalar.
// Phase 2 identical MFMA.
// ---------------------------------------------------------------------------
__global__ __launch_bounds__(256, 2) void layer0_kernel(
    const float* __restrict__ xin, const int2* __restrict__ csr,
    const float* __restrict__ xsrc, const int* __restrict__ rowSt,
    const float* __restrict__ AN, const float* __restrict__ BN,
    const unsigned* __restrict__ AB, const int* __restrict__ segsel,
    const short* __restrict__ WT, const float* __restrict__ bias,
    u16* __restrict__ houtbf, int N) {
  __shared__ u16 As[16][264];
  __shared__ int2 ecache[4][256];
  __shared__ float xcache[4][256];
  int wv = threadIdx.x >> 6, lane = threadIdx.x & 63;
  int nbase = blockIdx.x * 16;
  int d0 = lane * 4;
  int v0 = nbase + wv * 4;

  int segEN = segsel[0], segEP = segsel[1];
  int segNN = segsel[2], segNP = segsel[3];
  // node-table rows (f32), 4 dims/lane
  f32x4 AxN = *(const f32x4*)(AN + (size_t)segNN * 256 + d0);
  f32x4 BxN = *(const f32x4*)(BN + (size_t)segNN * 256 + d0);
  f32x4 AxP = *(const f32x4*)(AN + (size_t)segNP * 256 + d0);
  f32x4 BxP = *(const f32x4*)(BN + (size_t)segNP * 256 + d0);
  // edge-table rows (bf16-packed, unpacked to f32)
  f32x4 AeN, BeN, AeP, BeP;
  {
    uint4v n0 = *(const uint4v*)(AB + (size_t)segEN * 256 + d0);
    uint4v p0 = *(const uint4v*)(AB + (size_t)segEP * 256 + d0);
#pragma unroll
    for (int j = 0; j < 4; ++j) {
      AeN[j] = __uint_as_float(n0[j] << 16);
      BeN[j] = __uint_as_float(n0[j] & 0xFFFF0000u);
      AeP[j] = __uint_as_float(p0[j] << 16);
      BeP[j] = __uint_as_float(p0[j] & 0xFFFF0000u);
    }
  }

  int rv0 = rowSt[v0], rv1 = rowSt[v0 + 1], rv2 = rowSt[v0 + 2];
  int rv3 = rowSt[v0 + 3], rv4 = rowSt[v0 + 4];
  int range = rv4 - rv0;
  bool fits = (range <= 256);
  if (fits) {
    for (int s = lane; s < range; s += 64) {
      ecache[wv][s] = csr[(size_t)rv0 + s];
      xcache[wv][s] = xsrc[(size_t)rv0 + s];
    }
  }

  for (int i = 0; i < 4; ++i) {
    int v = v0 + i;
    int lo = ((i == 0) ? rv0 : (i == 1) ? rv1 : (i == 2) ? rv2 : rv3);
    int hi = ((i == 0) ? rv1 : (i == 1) ? rv2 : (i == 2) ? rv3 : rv4);
    int deg = hi - lo;
    float xv = xin[v];
    bool vp = (xv > 0.0f);
    float de = (float)deg * EPS_F;
    f32x4 acc;
#pragma unroll
    for (int j = 0; j < 4; ++j)
      acc[j] = fmaf(vp ? AxP[j] : AxN[j], xv, vp ? BxP[j] : BxN[j]) + de;
    for (int p = lo; p < hi; ++p) {
      int2 e;
      float xs;
      if (fits) { e = ecache[wv][p - rv0]; xs = xcache[wv][p - rv0]; }
      else      { e = csr[(size_t)p];      xs = xsrc[(size_t)p]; }
      float xe = __int_as_float(e.y);
      int gk = e.x >> 17;
      bool sp = (xs > 0.0f);
      f32x4 Ae = (gk == segEN) ? AeN : AeP;
      f32x4 Be = (gk == segEN) ? BeN : BeP;
      if (__builtin_expect(gk != segEN && gk != segEP, 0)) {
        uint4v ab = *(const uint4v*)(AB + (size_t)gk * 256 + d0);
#pragma unroll
        for (int j = 0; j < 4; ++j) {
          Ae[j] = __uint_as_float(ab[j] << 16);
          Be[j] = __uint_as_float(ab[j] & 0xFFFF0000u);
        }
      }
#pragma unroll
      for (int j = 0; j < 4; ++j) {
        float hs = fmaf(sp ? AxP[j] : AxN[j], xs, sp ? BxP[j] : BxN[j]);
        float t = hs + fmaf(Ae[j], xe, Be[j]);
        acc[j] += fmaxf(t, 0.0f);
      }
    }
    ushort4v ob;
    ob.x = (u16)f2bf(acc.x); ob.y = (u16)f2bf(acc.y);
    ob.z = (u16)f2bf(acc.z); ob.w = (u16)f2bf(acc.w);
    *(ushort4v*)&As[wv * 4 + i][d0] = ob;
  }
  __syncthreads();

  // ---- phase 2: [16,256] @ [256,256] ----
  int colb = lane & 15, rowf = lane & 15, kgrp = (lane >> 4) * 8;
  int c0 = wv * 64;
  const short* wtc = WT + (size_t)(c0 + colb) * 256;
  const u16* Ar = &As[rowf][0];
  f32x4 acc0 = {0.f, 0.f, 0.f, 0.f}, acc1 = acc0, acc2 = acc0, acc3 = acc0;
  short8 b0 = *(const short8*)(wtc + kgrp);
  short8 b1 = *(const short8*)(wtc + 4096 + kgrp);
  short8 b2 = *(const short8*)(wtc + 8192 + kgrp);
  short8 b3 = *(const short8*)(wtc + 12288 + kgrp);
#pragma unroll
  for (int kt = 0; kt < 8; ++kt) {
    int k0 = kt * 32 + kgrp;
    short8 af = *(const short8*)(Ar + k0);
    short8 n0, n1, n2, n3;
    if (kt < 7) {
      int kn = k0 + 32;
      n0 = *(const short8*)(wtc + kn);
      n1 = *(const short8*)(wtc + 4096 + kn);
      n2 = *(const short8*)(wtc + 8192 + kn);
      n3 = *(const short8*)(wtc + 12288 + kn);
    }
    acc0 = __builtin_amdgcn_mfma_f32_16x16x32_bf16(af, b0, acc0, 0, 0, 0);
    acc1 = __builtin_amdgcn_mfma_f32_16x16x32_bf16(af, b1, acc1, 0, 0, 0);
    acc2 = __builtin_amdgcn_mfma_f32_16x16x32_bf16(af, b2, acc2, 0, 0, 0);
    acc3 = __builtin_amdgcn_mfma_f32_16x16x32_bf16(af, b3, acc3, 0, 0, 0);
    if (kt < 7) { b0 = n0; b1 = n1; b2 = n2; b3 = n3; }
  }
  int rbase = (lane >> 4) * 4;
#pragma unroll
  for (int nbk = 0; nbk < 4; ++nbk) {
    f32x4 a = (nbk == 0) ? acc0 : (nbk == 1) ? acc1 : (nbk == 2) ? acc2 : acc3;
    int col = c0 + nbk * 16 + colb;
    float bv = bias[col];
#pragma unroll
    for (int rr = 0; rr < 4; ++rr) {
      int vv = nbase + rbase + rr;
      if (vv < N) houtbf[(size_t)vv * 256 + col] = (u16)f2bf(a[rr] + bv);
    }
  }
}

// ---------------------------------------------------------------------------
// Fused layer (r10/r12 measured-good config) for layers 1..3.
// Phase 1: LDS edge-cache + paired gathers (lanes 0-31 edge A, 32-63 edge B).
// NOTE: launch_bounds(256,2) -- do NOT raise min-waves (r11: spill, 2x dur).
// ---------------------------------------------------------------------------
#define PAIR_FETCH(k)                                                              \
  int si##k = p + 2 * (k) + half; si##k = (si##k < hi) ? si##k : hi - 1;           \
  int2 e##k = ec[si##k];                                                           \
  ushort8v hv##k = *(const ushort8v*)(hbf + (size_t)(e##k.x & 0x1FFFF) * 256 + dl);

#define PAIR_COMP(k) {                                                             \
    float mk = (p + 2 * (k) + half < hi) ? 1.0f : 0.0f;                            \
    float xk = __int_as_float(e##k.y);                                             \
    int gk = e##k.x >> 17;                                                         \
    if (__builtin_expect(__ballot(gk != segN && gk != segP) != 0ull, 0)) {         \
      uint4v ab0 = *(const uint4v*)(AB + (size_t)gk * 256 + dl);                   \
      uint4v ab1 = *(const uint4v*)(AB + (size_t)gk * 256 + dl + 4);               \
      _Pragma("unroll") for (int j = 0; j < 8; ++j) {                              \
        unsigned abj = (j < 4) ? ab0[j] : ab1[j - 4];                              \
        float Ae = __uint_as_float(abj << 16);                                     \
        float Be = __uint_as_float(abj & 0xFFFF0000u);                             \
        float tt = bf2f(hv##k[j]) + fmaf(Ae, xk, Be);                              \
        acc[j] = fmaf(mk, fmaxf(tt, 0.0f), acc[j]);                                \
      }                                                                            \
    } else {                                                                       \
      bool isN = (gk == segN);                                                     \
      _Pragma("unroll") for (int j = 0; j < 8; ++j) {                              \
        float Ae = isN ? An[j] : Ap[j];                                            \
        float Be = isN ? Bn[j] : Bp[j];                                            \
        float tt = bf2f(hv##k[j]) + fmaf(Ae, xk, Be);                              \
        acc[j] = fmaf(mk, fmaxf(tt, 0.0f), acc[j]);                                \
      }                                                                            \
    }                                                                              \
  }

__global__ __launch_bounds__(256, 2) void layer_kernel(
    const u16* __restrict__ hbf, const int2* __restrict__ csr,
    const int* __restrict__ rowSt,
    const unsigned* __restrict__ AB, const int* __restrict__ segsel,
    const short* __restrict__ WT, const float* __restrict__ bias,
    u16* __restrict__ houtbf, float* __restrict__ outp,
    const float* __restrict__ ow3, const float* __restrict__ ob3, int N) {
  __shared__ u16 As[16][264];
  __shared__ int2 ecache[4][256];
  __shared__ float sw[768];
  __shared__ float sh[4][16][3];
  int wv = threadIdx.x >> 6, lane = threadIdx.x & 63;
  int nbase = blockIdx.x * 16;
  int d0 = lane * 4;
  int v0 = nbase + wv * 4;
  int half = lane >> 5;
  int dl = (lane & 31) * 8;

  if (outp) {  // preload head weights (block-uniform branch)
    for (int i = threadIdx.x; i < 768; i += 256) sw[i] = ow3[i];
  }

  int segN = segsel[0], segP = segsel[1];
  // pre-unpack (A,B) for the two live segments, 8 dims per lane (dl..dl+7)
  f32x8 An, Bn, Ap, Bp;
  {
    uint4v n0 = *(const uint4v*)(AB + (size_t)segN * 256 + dl);
    uint4v n1 = *(const uint4v*)(AB + (size_t)segN * 256 + dl + 4);
    uint4v p0v = *(const uint4v*)(AB + (size_t)segP * 256 + dl);
    uint4v p1v = *(const uint4v*)(AB + (size_t)segP * 256 + dl + 4);
#pragma unroll
    for (int j = 0; j < 8; ++j) {
      unsigned nj = (j < 4) ? n0[j] : n1[j - 4];
      unsigned pj = (j < 4) ? p0v[j] : p1v[j - 4];
      An[j] = __uint_as_float(nj << 16);
      Bn[j] = __uint_as_float(nj & 0xFFFF0000u);
      Ap[j] = __uint_as_float(pj << 16);
      Bp[j] = __uint_as_float(pj & 0xFFFF0000u);
    }
  }

  int rv0 = rowSt[v0], rv1 = rowSt[v0 + 1], rv2 = rowSt[v0 + 2];
  int rv3 = rowSt[v0 + 3], rv4 = rowSt[v0 + 4];
  int range = rv4 - rv0;
  const int2* ec = &ecache[wv][0];

  if (__builtin_expect(range <= 256, 1)) {
    for (int s = lane; s < range; s += 64) ecache[wv][s] = csr[(size_t)rv0 + s];
    for (int i = 0; i < 4; ++i) {
      int v = v0 + i;
      int lo = ((i == 0) ? rv0 : (i == 1) ? rv1 : (i == 2) ? rv2 : rv3) - rv0;
      int hi = ((i == 0) ? rv1 : (i == 1) ? rv2 : (i == 2) ? rv3 : rv4) - rv0;
      int deg = hi - lo;
      ushort8v sv = *(const ushort8v*)(hbf + (size_t)v * 256 + dl);
      float de = (float)deg * EPS_F;
      f32x8 acc = {0.f, 0.f, 0.f, 0.f, 0.f, 0.f, 0.f, 0.f};
      for (int p = lo; p < hi; p += 8) {  // 4 pairs = 8 edges per iteration
        PAIR_FETCH(0); PAIR_FETCH(1); PAIR_FETCH(2); PAIR_FETCH(3);
        PAIR_COMP(0); PAIR_COMP(1); PAIR_COMP(2); PAIR_COMP(3);
      }
      ushort8v ob;
#pragma unroll
      for (int j = 0; j < 8; ++j) {
        float tot = acc[j] + __shfl_xor(acc[j], 32);
        ob[j] = (u16)f2bf(bf2f(sv[j]) + de + tot);
      }
      if (half == 0) *(ushort8v*)&As[wv * 4 + i][dl] = ob;
    }
  } else {
    // rare fallback: direct 1-wide loop from global csr (4-dims/lane form)
    for (int i = 0; i < 4; ++i) {
      int v = v0 + i;
      int lo = (i == 0) ? rv0 : (i == 1) ? rv1 : (i == 2) ? rv2 : rv3;
      int hi = (i == 0) ? rv1 : (i == 1) ? rv2 : (i == 2) ? rv3 : rv4;
      int deg = hi - lo;
      ushort4v sv = *(const ushort4v*)(hbf + (size_t)v * 256 + d0);
      float de = (float)deg * EPS_F;
      f32x4 acc;
      acc.x = bf2f(sv.x) + de; acc.y = bf2f(sv.y) + de;
      acc.z = bf2f(sv.z) + de; acc.w = bf2f(sv.w) + de;
      for (int p = lo; p < hi; ++p) {
        int2 e = csr[(size_t)p];
        ushort4v hv = *(const ushort4v*)(hbf + (size_t)(e.x & 0x1FFFF) * 256 + d0);
        float x = __int_as_float(e.y);
        int g = __builtin_amdgcn_readfirstlane(e.x) >> 17;
        f32x4 Ae, Be;
        uint4v ab = *(const uint4v*)(AB + (size_t)g * 256 + d0);
#pragma unroll
        for (int j = 0; j < 4; ++j) {
          Ae[j] = __uint_as_float(ab[j] << 16);
          Be[j] = __uint_as_float(ab[j] & 0xFFFF0000u);
        }
#pragma unroll
        for (int j = 0; j < 4; ++j)
          acc[j] += fmaxf(bf2f(hv[j]) + fmaf(Ae[j], x, Be[j]), 0.0f);
      }
      ushort4v ob;
      ob.x = (u16)f2bf(acc.x); ob.y = (u16)f2bf(acc.y);
      ob.z = (u16)f2bf(acc.z); ob.w = (u16)f2bf(acc.w);
      *(ushort4v*)&As[wv * 4 + i][d0] = ob;
    }
  }
  __syncthreads();

  // ---- phase 2: [16,256] @ [256,256] ----
  int colb = lane & 15, rowf = lane & 15, kgrp = (lane >> 4) * 8;
  int c0 = wv * 64;
  const short* wtc = WT + (size_t)(c0 + colb) * 256;
  const u16* Ar = &As[rowf][0];
  f32x4 acc0 = {0.f, 0.f, 0.f, 0.f}, acc1 = acc0, acc2 = acc0, acc3 = acc0;
  short8 b0 = *(const short8*)(wtc + kgrp);
  short8 b1 = *(const short8*)(wtc + 4096 + kgrp);
  short8 b2 = *(const short8*)(wtc + 8192 + kgrp);
  short8 b3 = *(const short8*)(wtc + 12288 + kgrp);
#pragma unroll
  for (int kt = 0; kt < 8; ++kt) {
    int k0 = kt * 32 + kgrp;
    short8 af = *(const short8*)(Ar + k0);
    short8 n0, n1, n2, n3;
    if (kt < 7) {
      int kn = k0 + 32;
      n0 = *(const short8*)(wtc + kn);
      n1 = *(const short8*)(wtc + 4096 + kn);
      n2 = *(const short8*)(wtc + 8192 + kn);
      n3 = *(const short8*)(wtc + 12288 + kn);
    }
    acc0 = __builtin_amdgcn_mfma_f32_16x16x32_bf16(af, b0, acc0, 0, 0, 0);
    acc1 = __builtin_amdgcn_mfma_f32_16x16x32_bf16(af, b1, acc1, 0, 0, 0);
    acc2 = __builtin_amdgcn_mfma_f32_16x16x32_bf16(af, b2, acc2, 0, 0, 0);
    acc3 = __builtin_amdgcn_mfma_f32_16x16x32_bf16(af, b3, acc3, 0, 0, 0);
    if (kt < 7) { b0 = n0; b1 = n1; b2 = n2; b3 = n3; }
  }
  int rbase = (lane >> 4) * 4;
  if (houtbf) {
#pragma unroll
    for (int nbk = 0; nbk < 4; ++nbk) {
      f32x4 a = (nbk == 0) ? acc0 : (nbk == 1) ? acc1 : (nbk == 2) ? acc2 : acc3;
      int col = c0 + nbk * 16 + colb;
      float bv = bias[col];
#pragma unroll
      for (int rr = 0; rr < 4; ++rr) {
        int vv = nbase + rbase + rr;
        if (vv < N) houtbf[(size_t)vv * 256 + col] = (u16)f2bf(a[rr] + bv);
      }
    }
  }
  if (outp) {  // fused head: project 16x256 block result to 16x3
    float p[4][3];
#pragma unroll
    for (int rr = 0; rr < 4; ++rr) {
      p[rr][0] = 0.f; p[rr][1] = 0.f; p[rr][2] = 0.f;
    }
#pragma unroll
    for (int nbk = 0; nbk < 4; ++nbk) {
      f32x4 a = (nbk == 0) ? acc0 : (nbk == 1) ? acc1 : (nbk == 2) ? acc2 : acc3;
      int col = c0 + nbk * 16 + colb;
      float bv = bias[col];
#pragma unroll
      for (int rr = 0; rr < 4; ++rr) {
        float val = a[rr] + bv;
#pragma unroll
        for (int o = 0; o < 3; ++o) p[rr][o] = fmaf(val, sw[col * 3 + o], p[rr][o]);
      }
    }
#pragma unroll
    for (int rr = 0; rr < 4; ++rr)
#pragma unroll
      for (int o = 0; o < 3; ++o) {
        float s = p[rr][o];
        s += __shfl_xor(s, 1, 16);
        s += __shfl_xor(s, 2, 16);
        s += __shfl_xor(s, 4, 16);
        s += __shfl_xor(s, 8, 16);
        if (colb == 0) sh[wv][rbase + rr][o] = s;
      }
    __syncthreads();
    int t = threadIdx.x;
    if (t < 48) {
      int row = t / 3, o = t % 3;
      float s = sh[0][row][o] + sh[1][row][o] + sh[2][row][o] + sh[3][row][o] + ob3[o];
      int vv = nbase + row;
      if (vv < N) outp[(size_t)vv * 3 + o] = s;
    }
  }
}

// ---------------------------------------------------------------------------
extern "C" void kernel_launch(void* const* d_in, const int* in_sizes, int n_in,
                              void* d_out, int out_size, void* d_ws, size_t ws_size,
                              hipStream_t stream) {
  const float* x     = (const float*)d_in[0];
  const float* eattr = (const float*)d_in[1];
  const int*   eidx  = (const int*)d_in[2];
  const float* nw1 = (const float*)d_in[3];
  const float* nb1 = (const float*)d_in[4];
  const float* nw2 = (const float*)d_in[5];
  const float* nb2 = (const float*)d_in[6];
  const float* ew1 = (const float*)d_in[7];
  const float* eb1 = (const float*)d_in[8];
  const float* ew2 = (const float*)d_in[9];
  const float* eb2 = (const float*)d_in[10];
  const float* gw  = (const float*)d_in[11];
  const float* gb  = (const float*)d_in[12];
  const float* ow  = (const float*)d_in[13];
  const float* ob  = (const float*)d_in[14];

  int N = in_sizes[0];
  int E = in_sizes[1];
  const int* srcA = eidx;
  const int* dstA = eidx + E;

  char* ws = (char*)d_ws;
  auto al = [](size_t v) { return (v + 255) & ~(size_t)255; };
  size_t off = 0;
  u16* hbfA    = (u16*)(ws + off);   off = al(off + (size_t)N * 256 * 2);
  u16* hbfB    = (u16*)(ws + off);   off = al(off + (size_t)N * 256 * 2);
  short* WT    = (short*)(ws + off); off = al(off + (size_t)4 * 256 * 256 * 2);
  float* knN   = (float*)(ws + off); off = al(off + 128 * 4);
  float* AN    = (float*)(ws + off); off = al(off + 129 * 256 * 4);
  float* BN    = (float*)(ws + off); off = al(off + 129 * 256 * 4);
  float* knE   = (float*)(ws + off); off = al(off + 128 * 4);
  unsigned* ABE = (unsigned*)(ws + off); off = al(off + 129 * 256 * 4);
  int* rankN   = (int*)(ws + off);   off = al(off + 128 * 4);
  int* act0N   = (int*)(ws + off);   off = al(off + 128 * 4);
  int* rankE   = (int*)(ws + off);   off = al(off + 128 * 4);
  int* act0E   = (int*)(ws + off);   off = al(off + 128 * 4);
  int* segsel  = (int*)(ws + off);   off = al(off + 4 * 4);
  int* rowSt   = (int*)(ws + off);   off = al(off + (size_t)(N + 1) * 4);
  int* counts  = (int*)(ws + off);   off = al(off + (size_t)N * 4);
  int* bsums   = (int*)(ws + off);   off = al(off + 256 * 4);
  int2* csr    = (int2*)(ws + off);  off = al(off + (size_t)E * 8);
  float* xsrc  = (float*)(ws + off); off = al(off + (size_t)E * 4);
  (void)ws_size; (void)n_in; (void)out_size;

  int gN = (N + 255) / 256, gE = (E + 255) / 256;

  // encoder tables (merged builds)
  build_meta2_kernel<<<2, 128, 0, stream>>>(nw1, nb1, ew1, eb1, knN, rankN, act0N,
                                            knE, rankE, act0E, segsel);
  build_seg2_kernel<<<258, 256, 0, stream>>>(nw1, nb1, nw2, nb2, ew1, eb1, ew2, eb2,
                                             rankN, act0N, rankE, act0E, AN, BN, ABE);

  // counts zero + weight convert (one dispatch)
  prep_fused_kernel<<<gN + 1024, 256, 0, stream>>>(N, gN, counts, gw, WT);

  // CSR build (+ per-slot x_src for layer 0)
  hist_kernel<<<gE, 256, 0, stream>>>(dstA, E, counts);
  scan_p1_kernel<<<gN, 256, 0, stream>>>(counts, N, bsums);
  scan_p2_kernel<<<1, 256, 0, stream>>>(bsums, gN, rowSt, N);
  scan_p3_kernel<<<gN, 256, 0, stream>>>(counts, N, bsums, rowSt);
  zero_kernel<<<gN, 256, 0, stream>>>(counts, N);
  fill_kernel<<<gE, 256, 0, stream>>>(srcA, dstA, eattr, x, E, rowSt, counts, knE,
                                      csr, xsrc);

  int gLayer = (N + 15) / 16;

  // layer 0: gather-free (h = node-table(x_src) computed in registers)
  layer0_kernel<<<gLayer, 256, 0, stream>>>(x, csr, xsrc, rowSt, AN, BN, ABE, segsel,
                                            WT, gb, hbfA, N);

  // layers 1..3 (last layer also applies the output head)
  u16* hbc = hbfA;
  u16* hbn = hbfB;
  for (int l = 1; l < 4; ++l) {
    u16* hbo = (l == 3) ? nullptr : hbn;
    float* op = (l == 3) ? (float*)d_out : nullptr;
    layer_kernel<<<gLayer, 256, 0, stream>>>(hbc, csr, rowSt, ABE, segsel,
                                             WT + (size_t)l * 256 * 256,
                                             gb + (size_t)l * 256, hbo, op, ow, ob, N);
    u16* t = hbc; hbc = hbn; hbn = t;
  }
}